// Round 16
// baseline (293.475 us; speedup 1.0000x reference)
//
#include <hip/hip_runtime.h>
#include <math.h>

// ---------------------------------------------------------------------------
// GCN encoder forward, bf16 MFMA formulation.
// Setup DAG (5 fused kernels, r12 structure) then:
//   gemm1 (xb@W1 -> h16)
//   fusedA: per 64-row block: gather h1 rows from h16 -> swizzled LDS tile;
//           gemm2([xb,noise,h1LDS]) -> hs2 (d_out)
//   fusedB: gather h2 rows from hs2 -> LDS; gemm3([xb,h2LDS]) -> tms (h16)
//   gather_dual: tms -> zm,zs (d_out)
// Gather->GEMM fusion: gather output rows ARE the next GEMM's A rows (row-
// local), so h1/h2 never touch global memory; gather (latency-bound) and
// MFMA phases overlap across blocks.
// ---------------------------------------------------------------------------

typedef short bf16x8 __attribute__((ext_vector_type(8)));
typedef float f32x4 __attribute__((ext_vector_type(4)));
typedef float f32x2 __attribute__((ext_vector_type(2)));

#define BN_G 1024
#define SCAN_BLK 256
#define SCAN_ELEMS 1024

__device__ inline unsigned short f2bf(float f) {  // RNE
    unsigned int u = __builtin_bit_cast(unsigned int, f);
    u += 0x7fff + ((u >> 16) & 1);
    return (unsigned short)(u >> 16);
}
__device__ inline unsigned int pack2(float lo, float hi) {
    return ((unsigned int)f2bf(hi) << 16) | f2bf(lo);
}
__device__ inline f32x2 unp(unsigned int u) {
    return (f32x2){__builtin_bit_cast(float, u << 16),
                   __builtin_bit_cast(float, u & 0xffff0000u)};
}
__device__ inline void acc8v(f32x2* a, uint4 v) {   // vector adds -> v_pk_add_f32
    a[0] += unp(v.x); a[1] += unp(v.y); a[2] += unp(v.z); a[3] += unp(v.w);
}

__device__ __forceinline__ void gload_lds16(const void* g, void* l) {
    __builtin_amdgcn_global_load_lds(
        (const __attribute__((address_space(1))) unsigned int*)g,
        (__attribute__((address_space(3))) unsigned int*)l, 16, 0, 0);
}

// ---------------------------------------------------------------------------
// fused1 (r12 ordering): blocks [0,BN_G) = bn_stats ; [BN_G,+EB) = count_deg
// ---------------------------------------------------------------------------
__global__ __launch_bounds__(256) void fused1(const float4* __restrict__ x4,
                                              float* __restrict__ partials, int n,
                                              const int* __restrict__ ei,
                                              int* __restrict__ cnt,
                                              int* __restrict__ slot, int E) {
    __shared__ float4 lds[2][8][32];
    int bid = blockIdx.x, t = threadIdx.x;
    if (bid < BN_G) {
        int cg = t & 31;
        int rs = t >> 5;
        float4 s = make_float4(0.f, 0.f, 0.f, 0.f);
        float4 q = make_float4(0.f, 0.f, 0.f, 0.f);
        const float4 z4 = make_float4(0.f, 0.f, 0.f, 0.f);
        const int stride = BN_G * 32;
        for (int r0 = bid * 32 + rs * 4; r0 < n; r0 += stride) {
            float4 v0 = x4[(size_t)r0 * 32 + cg];
            float4 v1 = (r0 + 1 < n) ? x4[(size_t)(r0 + 1) * 32 + cg] : z4;
            float4 v2 = (r0 + 2 < n) ? x4[(size_t)(r0 + 2) * 32 + cg] : z4;
            float4 v3 = (r0 + 3 < n) ? x4[(size_t)(r0 + 3) * 32 + cg] : z4;
            s.x += v0.x + v1.x + v2.x + v3.x;
            s.y += v0.y + v1.y + v2.y + v3.y;
            s.z += v0.z + v1.z + v2.z + v3.z;
            s.w += v0.w + v1.w + v2.w + v3.w;
            q.x = fmaf(v0.x, v0.x, fmaf(v1.x, v1.x, fmaf(v2.x, v2.x, fmaf(v3.x, v3.x, q.x))));
            q.y = fmaf(v0.y, v0.y, fmaf(v1.y, v1.y, fmaf(v2.y, v2.y, fmaf(v3.y, v3.y, q.y))));
            q.z = fmaf(v0.z, v0.z, fmaf(v1.z, v1.z, fmaf(v2.z, v2.z, fmaf(v3.z, v3.z, q.z))));
            q.w = fmaf(v0.w, v0.w, fmaf(v1.w, v1.w, fmaf(v2.w, v2.w, fmaf(v3.w, v3.w, q.w))));
        }
        lds[0][rs][cg] = s;
        lds[1][rs][cg] = q;
        __syncthreads();
        if (t < 64) {
            int which = t >> 5;
            int c = t & 31;
            float4 a = lds[which][0][c];
#pragma unroll
            for (int i = 1; i < 8; i++) {
                float4 b = lds[which][i][c];
                a.x += b.x; a.y += b.y; a.z += b.z; a.w += b.w;
            }
            int base = which * 128 + c * 4;
            partials[(size_t)(base + 0) * BN_G + bid] = a.x;
            partials[(size_t)(base + 1) * BN_G + bid] = a.y;
            partials[(size_t)(base + 2) * BN_G + bid] = a.z;
            partials[(size_t)(base + 3) * BN_G + bid] = a.w;
        }
        return;
    }
    int e = (bid - BN_G) * 256 + t;
    if (e < E) slot[e] = atomicAdd(&cnt[ei[E + e]], 1);
}

// ---------------------------------------------------------------------------
// fused2: blocks [0,256) = bn_reduce ; [256, 256+nb) = scan_blocks
// ---------------------------------------------------------------------------
__global__ __launch_bounds__(256) void fused2(const float4* __restrict__ partials4,
                                              float* __restrict__ stats,
                                              const int* __restrict__ cnt,
                                              int* __restrict__ row_ptr,
                                              int* __restrict__ bsums, int n) {
    __shared__ float red[256];
    __shared__ int lds[SCAN_BLK];
    int t = threadIdx.x;
    if (blockIdx.x < 256) {
        int c = blockIdx.x;
        float4 v = partials4[(size_t)c * (BN_G / 4) + t];
        red[t] = v.x + v.y + v.z + v.w;
        __syncthreads();
        for (int off = 128; off > 0; off >>= 1) {
            if (t < off) red[t] += red[t + off];
            __syncthreads();
        }
        if (t == 0) stats[c] = red[0];
    } else {
        int blk = blockIdx.x - 256;
        int base = blk * SCAN_ELEMS;
        int v[4];
        int s = 0;
#pragma unroll
        for (int j = 0; j < 4; j++) {
            int i = base + t * 4 + j;
            v[j] = s;
            s += (i < n) ? cnt[i] : 0;
        }
        lds[t] = s;
        __syncthreads();
        for (int off = 1; off < SCAN_BLK; off <<= 1) {
            int val = (t >= off) ? lds[t - off] : 0;
            __syncthreads();
            lds[t] += val;
            __syncthreads();
        }
        int excl = (t == 0) ? 0 : lds[t - 1];
#pragma unroll
        for (int j = 0; j < 4; j++) {
            int i = base + t * 4 + j;
            if (i < n) row_ptr[i] = excl + v[j];
        }
        if (t == SCAN_BLK - 1) bsums[blk] = lds[t];
    }
}

// ---------------------------------------------------------------------------
// fused3 (1 block): t==0 serial-scans bsums ; t in [128,256) bn_finalize
// ---------------------------------------------------------------------------
__global__ void fused3(int* __restrict__ bsums, int nb,
                       const float* __restrict__ stats,
                       const float* __restrict__ gamma, const float* __restrict__ beta,
                       float* __restrict__ scale, float* __restrict__ shift, float invN) {
    int t = threadIdx.x;
    if (t == 0) {
        int acc = 0;
        for (int i = 0; i < nb; i++) { int c = bsums[i]; bsums[i] = acc; acc += c; }
    } else if (t >= 128 && t < 256) {
        int c = t - 128;
        float mu = stats[c] * invN;
        float var = stats[128 + c] * invN - mu * mu;
        float sc = gamma[c] / sqrtf(var + 1e-5f);
        scale[c] = sc;
        shift[c] = beta[c] - mu * sc;
    }
}

// ---------------------------------------------------------------------------
// fused4: scan_add + dinv in one pass over nodes
// ---------------------------------------------------------------------------
__global__ void fused4(int* __restrict__ row_ptr, const int* __restrict__ bsums,
                       const int* __restrict__ cnt, float* __restrict__ dinv,
                       int n, int E) {
    int i = blockIdx.x * blockDim.x + threadIdx.x;
    if (i < n) {
        row_ptr[i] += bsums[i / SCAN_ELEMS];
        dinv[i] = rsqrtf((float)cnt[i] + 1.0f);
    }
    if (i == 0) row_ptr[n] = E;
}

// ---------------------------------------------------------------------------
// pack W (fp32 [K][C], col slice at colOff) into MFMA fragment layout.
// ---------------------------------------------------------------------------
__device__ inline void pack_body(int i, const float* __restrict__ W,
                                 unsigned short* __restrict__ Wp,
                                 int K, int C, int colOff) {
    if (i >= K * C) return;
    int k = i / C, c = i % C;
    int gc = c + colOff;
    int s = k >> 7, kc = (k >> 5) & 3, lhi = (k >> 3) & 3, j = k & 7;
    int wc = gc >> 6, n = (gc >> 4) & 3, l15 = gc & 15;
    int lane = lhi * 16 + l15;
    size_t dst = ((size_t)((s * 2 + wc) * 4 + kc) * 4 + n) * 512 + lane * 8 + j;
    Wp[dst] = f2bf(W[i]);
}

// ---------------------------------------------------------------------------
// fused5: fill_edges || convert_inputs (x and noise) || pack_w x4
// ---------------------------------------------------------------------------
__global__ __launch_bounds__(256) void fused5(
    const int* __restrict__ ei, const int* __restrict__ row_ptr,
    const int* __restrict__ slot, int* __restrict__ edge_src, int E, int EB,
    const float4* __restrict__ x4, const float4* __restrict__ n4,
    const float* __restrict__ scale, const float* __restrict__ shift,
    ushort4* __restrict__ xb, ushort4* __restrict__ nb4, int total4, int CB,
    const float* __restrict__ W1, unsigned short* __restrict__ Wp1,
    const float* __restrict__ W2, unsigned short* __restrict__ Wp2,
    const float* __restrict__ Wm, const float* __restrict__ Ws,
    unsigned short* __restrict__ Wpc)
{
    int bid = blockIdx.x, t = threadIdx.x;
    if (bid < EB) {
        int e = bid * 256 + t;
        if (e < E) {
            int s = ei[e], d = ei[E + e];
            edge_src[row_ptr[d] + slot[e]] = s;
        }
        return;
    }
    bid -= EB;
    if (bid < CB) {
        int i = bid * 256 + t;
        if (i < total4) {
            int c4 = (i & 31) << 2;
            float4 sc = *reinterpret_cast<const float4*>(scale + c4);
            float4 sh = *reinterpret_cast<const float4*>(shift + c4);
            float4 v = x4[i];
            ushort4 o;
            o.x = f2bf(fmaf(v.x, sc.x, sh.x));
            o.y = f2bf(fmaf(v.y, sc.y, sh.y));
            o.z = f2bf(fmaf(v.z, sc.z, sh.z));
            o.w = f2bf(fmaf(v.w, sc.w, sh.w));
            xb[i] = o;
            float4 w = n4[i];
            ushort4 p;
            p.x = f2bf(w.x); p.y = f2bf(w.y); p.z = f2bf(w.z); p.w = f2bf(w.w);
            nb4[i] = p;
        }
        return;
    }
    bid -= CB;
    if (bid < 64)  { pack_body(bid * 256 + t, W1, Wp1, 128, 128, 0); return; }
    bid -= 64;
    if (bid < 192) { pack_body(bid * 256 + t, W2, Wp2, 384, 128, 0); return; }
    bid -= 192;
    if (bid < 64)  { pack_body(bid * 256 + t, Wm, Wpc, 256, 64, 0); return; }
    bid -= 64;
    pack_body(bid * 256 + t, Ws, Wpc, 256, 64, 64);
}

// ---------------------------------------------------------------------------
// MFMA GEMM (global sources only): hs = (A @ W) * dinv[row]
// ---------------------------------------------------------------------------
template <int NSRC>
__global__ __launch_bounds__(256, 4) void gemm_mfma(
    const unsigned short* __restrict__ A0, const unsigned short* __restrict__ A1,
    const unsigned short* __restrict__ A2,
    const unsigned short* __restrict__ Wpk,
    const float* __restrict__ dinv, unsigned short* __restrict__ out)
{
    constexpr int NBUF = (NSRC > 1) ? 2 : 1;
    __shared__ unsigned char ldsA[NBUF][64 * 256];

    const int lane = threadIdx.x & 63;
    const int wid  = threadIdx.x >> 6;
    const int wr   = wid >> 1, wc = wid & 1;
    const int l15  = lane & 15, lhi = lane >> 4;
    const int c0   = wc * 64;
    const long rowblk = (long)blockIdx.x * 64;
    const int rl0 = wr * 32 + l15;
    const int rl1 = rl0 + 16;
    const int rsw = rl0 & 7;

    const unsigned short* __restrict__ srcs[3] = {A0, A1, A2};
    auto stage = [&](int s, int b) {
#pragma unroll
        for (int i = 0; i < 4; i++) {
            int G = (wid * 4 + i) * 64 + lane;
            int r = G >> 4, g = G & 15;
            const unsigned short* src = srcs[s] + (rowblk + r) * 128 + (g ^ (r & 7)) * 8;
            gload_lds16(src, &ldsA[b][G * 16]);
        }
    };

    f32x4 acc[2][4];
#pragma unroll
    for (int g = 0; g < 2; g++)
#pragma unroll
        for (int n = 0; n < 4; n++)
            acc[g][n] = (f32x4){0.f, 0.f, 0.f, 0.f};

    stage(0, 0);

#pragma unroll
    for (int s = 0; s < NSRC; s++) {
        const unsigned short* wbase = Wpk + ((size_t)(s * 2 + wc) * 16) * 512 + lane * 8;
        bf16x8 w[4][4];
#pragma unroll
        for (int kc = 0; kc < 4; kc++)
#pragma unroll
            for (int n = 0; n < 4; n++)
                w[kc][n] = *reinterpret_cast<const bf16x8*>(wbase + (kc * 4 + n) * 512);

        __syncthreads();
        if (s + 1 < NSRC) stage(s + 1, (s + 1) % NBUF);
        const unsigned char* bufp = ldsA[s % NBUF];

#pragma unroll
        for (int kc = 0; kc < 4; kc++) {
            int g0 = kc * 4 + lhi;
            bf16x8 a0 = *reinterpret_cast<const bf16x8*>(bufp + rl0 * 256 + (g0 ^ rsw) * 16);
            bf16x8 a1 = *reinterpret_cast<const bf16x8*>(bufp + rl1 * 256 + (g0 ^ rsw) * 16);
#pragma unroll
            for (int n = 0; n < 4; n++) {
                acc[0][n] = __builtin_amdgcn_mfma_f32_16x16x32_bf16(w[kc][n], a0, acc[0][n], 0, 0, 0);
                acc[1][n] = __builtin_amdgcn_mfma_f32_16x16x32_bf16(w[kc][n], a1, acc[1][n], 0, 0, 0);
            }
        }
    }

#pragma unroll
    for (int g = 0; g < 2; g++) {
        long row = rowblk + (g ? rl1 : rl0);
        float dv = dinv[row];
        unsigned short* op = out + row * 128 + c0 + lhi * 4;
#pragma unroll
        for (int n = 0; n < 4; n++) {
            f32x4 v = acc[g][n];
            ushort4 pk;
            pk.x = f2bf(v[0] * dv);
            pk.y = f2bf(v[1] * dv);
            pk.z = f2bf(v[2] * dv);
            pk.w = f2bf(v[3] * dv);
            *reinterpret_cast<ushort4*>(op + n * 16) = pk;
        }
    }
}

// ---------------------------------------------------------------------------
// Fused gather -> GEMM. NG global-staged sources; the LAST source is the
// gather result, built directly in the swizzled LDS A-tile.
// Gather: 16-lane group per node, 4 nodes/group (64 rows per block).
// h = relu(dinv[node]*(sum hsrc[src] + hsrc[node]) + gbias)
// Then gemm over NSRC=NG+1 sources -> out (*dinv[row]).
// ---------------------------------------------------------------------------
template <int NG>
__global__ __launch_bounds__(256, 3) void gather_gemm(
    const unsigned short* __restrict__ A0, const unsigned short* __restrict__ A1,
    const uint4* __restrict__ hsrc,
    const float* __restrict__ dinv, const int* __restrict__ row_ptr,
    const int* __restrict__ edge_src, const float* __restrict__ gbias,
    const unsigned short* __restrict__ Wpk,
    unsigned short* __restrict__ out, int n)
{
    constexpr int NSRC = NG + 1;
    __shared__ unsigned char ldsA[NG][64 * 256];
    __shared__ uint4 hlds[64 * 16];

    const int t = threadIdx.x;
    const int lane = t & 63;
    const int wid  = t >> 6;
    const int wr   = wid >> 1, wc = wid & 1;
    const int l15  = lane & 15, lhi = lane >> 4;
    const int c0   = wc * 64;
    const long rowblk = (long)blockIdx.x * 64;
    const int rl0 = wr * 32 + l15;
    const int rl1 = rl0 + 16;
    const int rsw = rl0 & 7;

    const unsigned short* __restrict__ srcs[2] = {A0, A1};
    auto stage = [&](int s, int b) {
#pragma unroll
        for (int i = 0; i < 4; i++) {
            int G = (wid * 4 + i) * 64 + lane;
            int r = G >> 4, g = G & 15;
            const unsigned short* src = srcs[s] + (rowblk + r) * 128 + (g ^ (r & 7)) * 8;
            gload_lds16(src, &ldsA[b][G * 16]);
        }
    };

    stage(0, 0);   // xb staging flies during the gather phase

    // ---- gather phase: group grp handles local rows grp*4 .. grp*4+3 ----
    {
        int grp = t >> 4, cl = t & 15;
#pragma unroll
        for (int i = 0; i < 4; i++) {
            int r = grp * 4 + i;
            long node = rowblk + r;
            uint4 o = make_uint4(0u, 0u, 0u, 0u);
            if (node < n) {
                int beg = row_ptr[node], end = row_ptr[node + 1];
                f32x2 a[4] = {(f32x2){0.f,0.f}, (f32x2){0.f,0.f},
                              (f32x2){0.f,0.f}, (f32x2){0.f,0.f}};
                f32x2 ab[4] = {(f32x2){0.f,0.f}, (f32x2){0.f,0.f},
                               (f32x2){0.f,0.f}, (f32x2){0.f,0.f}};
                acc8v(a, hsrc[(size_t)node * 16 + cl]);   // self-loop
                int e = beg;
                for (; e + 4 <= end; e += 4) {
                    uint4 v0 = hsrc[(size_t)edge_src[e] * 16 + cl];
                    uint4 v1 = hsrc[(size_t)edge_src[e + 1] * 16 + cl];
                    uint4 v2 = hsrc[(size_t)edge_src[e + 2] * 16 + cl];
                    uint4 v3 = hsrc[(size_t)edge_src[e + 3] * 16 + cl];
                    acc8v(a, v0);
                    acc8v(ab, v1);
                    acc8v(a, v2);
                    acc8v(ab, v3);
                }
                if (e + 2 <= end) {
                    uint4 v0 = hsrc[(size_t)edge_src[e] * 16 + cl];
                    uint4 v1 = hsrc[(size_t)edge_src[e + 1] * 16 + cl];
                    acc8v(a, v0);
                    acc8v(ab, v1);
                    e += 2;
                }
                if (e < end) acc8v(a, hsrc[(size_t)edge_src[e] * 16 + cl]);
#pragma unroll
                for (int j = 0; j < 4; j++) a[j] += ab[j];
                float dv = dinv[node];
                float4 b0 = *reinterpret_cast<const float4*>(gbias + cl * 8);
                float4 b1 = *reinterpret_cast<const float4*>(gbias + cl * 8 + 4);
                float r0 = fmaxf(fmaf(a[0].x, dv, b0.x), 0.f);
                float r1 = fmaxf(fmaf(a[0].y, dv, b0.y), 0.f);
                float r2 = fmaxf(fmaf(a[1].x, dv, b0.z), 0.f);
                float r3 = fmaxf(fmaf(a[1].y, dv, b0.w), 0.f);
                float r4 = fmaxf(fmaf(a[2].x, dv, b1.x), 0.f);
                float r5 = fmaxf(fmaf(a[2].y, dv, b1.y), 0.f);
                float r6 = fmaxf(fmaf(a[3].x, dv, b1.z), 0.f);
                float r7 = fmaxf(fmaf(a[3].y, dv, b1.w), 0.f);
                o.x = pack2(r0, r1); o.y = pack2(r2, r3);
                o.z = pack2(r4, r5); o.w = pack2(r6, r7);
            }
            hlds[r * 16 + (cl ^ (r & 7))] = o;   // swizzled A-tile layout
        }
    }

    // ---- GEMM phase ----
    f32x4 acc[2][4];
#pragma unroll
    for (int g = 0; g < 2; g++)
#pragma unroll
        for (int n = 0; n < 4; n++)
            acc[g][n] = (f32x4){0.f, 0.f, 0.f, 0.f};

#pragma unroll
    for (int s = 0; s < NSRC; s++) {
        const unsigned short* wbase = Wpk + ((size_t)(s * 2 + wc) * 16) * 512 + lane * 8;
        bf16x8 w[4][4];
#pragma unroll
        for (int kc = 0; kc < 4; kc++)
#pragma unroll
            for (int n = 0; n < 4; n++)
                w[kc][n] = *reinterpret_cast<const bf16x8*>(wbase + (kc * 4 + n) * 512);

        __syncthreads();                 // stage(s)/hlds + W(s) complete
        if (s + 1 < NG) stage(s + 1, s + 1);
        const unsigned char* bufp = (s < NG) ? ldsA[s]
                                             : reinterpret_cast<const unsigned char*>(hlds);

#pragma unroll
        for (int kc = 0; kc < 4; kc++) {
            int g0 = kc * 4 + lhi;
            bf16x8 a0 = *reinterpret_cast<const bf16x8*>(bufp + rl0 * 256 + (g0 ^ rsw) * 16);
            bf16x8 a1 = *reinterpret_cast<const bf16x8*>(bufp + rl1 * 256 + (g0 ^ rsw) * 16);
#pragma unroll
            for (int n = 0; n < 4; n++) {
                acc[0][n] = __builtin_amdgcn_mfma_f32_16x16x32_bf16(w[kc][n], a0, acc[0][n], 0, 0, 0);
                acc[1][n] = __builtin_amdgcn_mfma_f32_16x16x32_bf16(w[kc][n], a1, acc[1][n], 0, 0, 0);
            }
        }
    }

#pragma unroll
    for (int g = 0; g < 2; g++) {
        long row = rowblk + (g ? rl1 : rl0);
        float dv = dinv[row];
        unsigned short* op = out + row * 128 + c0 + lhi * 4;
#pragma unroll
        for (int n = 0; n < 4; n++) {
            f32x4 v = acc[g][n];
            ushort4 pk;
            pk.x = f2bf(v[0] * dv);
            pk.y = f2bf(v[1] * dv);
            pk.z = f2bf(v[2] * dv);
            pk.w = f2bf(v[3] * dv);
            *reinterpret_cast<ushort4*>(op + n * 16) = pk;
        }
    }
}

// ---------------------------------------------------------------------------
// final gather: t rows = [tm(64) | ts(64)] bf16 -> zm, zs fp32.
// one 16-lane group per node.
// ---------------------------------------------------------------------------
__global__ void gather_dual(const uint4* __restrict__ hs4, const float* __restrict__ dinv,
                            const int* __restrict__ row_ptr, const int* __restrict__ edge_src,
                            const float* __restrict__ bm, const float* __restrict__ bs,
                            float* __restrict__ zm, float* __restrict__ zs, int n) {
    int node = blockIdx.x * 16 + (threadIdx.x >> 4);
    if (node >= n) return;
    int cl = threadIdx.x & 15;
    int beg = row_ptr[node], end = row_ptr[node + 1];
    f32x2 a[4] = {(f32x2){0.f,0.f}, (f32x2){0.f,0.f}, (f32x2){0.f,0.f}, (f32x2){0.f,0.f}};
    f32x2 b[4] = {(f32x2){0.f,0.f}, (f32x2){0.f,0.f}, (f32x2){0.f,0.f}, (f32x2){0.f,0.f}};
    acc8v(a, hs4[(size_t)node * 16 + cl]);
    int e = beg;
    for (; e + 4 <= end; e += 4) {
        uint4 v0 = hs4[(size_t)edge_src[e] * 16 + cl];
        uint4 v1 = hs4[(size_t)edge_src[e + 1] * 16 + cl];
        uint4 v2 = hs4[(size_t)edge_src[e + 2] * 16 + cl];
        uint4 v3 = hs4[(size_t)edge_src[e + 3] * 16 + cl];
        acc8v(a, v0);
        acc8v(b, v1);
        acc8v(a, v2);
        acc8v(b, v3);
    }
    if (e + 2 <= end) {
        uint4 v0 = hs4[(size_t)edge_src[e] * 16 + cl];
        uint4 v1 = hs4[(size_t)edge_src[e + 1] * 16 + cl];
        acc8v(a, v0);
        acc8v(b, v1);
        e += 2;
    }
    if (e < end) acc8v(a, hs4[(size_t)edge_src[e] * 16 + cl]);
#pragma unroll
    for (int i = 0; i < 4; i++) a[i] += b[i];
    float dv = dinv[node];
    const float* bp = (cl < 8) ? (bm + cl * 8) : (bs + (cl - 8) * 8);
    float* zp = (cl < 8) ? (zm + (size_t)node * 64 + cl * 8)
                         : (zs + (size_t)node * 64 + (cl - 8) * 8);
    float4 b0 = *reinterpret_cast<const float4*>(bp);
    float4 b1 = *reinterpret_cast<const float4*>(bp + 4);
    float4 o0 = make_float4(fmaf(a[0].x, dv, b0.x), fmaf(a[0].y, dv, b0.y),
                            fmaf(a[1].x, dv, b0.z), fmaf(a[1].y, dv, b0.w));
    float4 o1 = make_float4(fmaf(a[2].x, dv, b1.x), fmaf(a[2].y, dv, b1.y),
                            fmaf(a[3].x, dv, b1.z), fmaf(a[3].y, dv, b1.w));
    *reinterpret_cast<float4*>(zp) = o0;
    *reinterpret_cast<float4*>(zp + 4) = o1;
}

// ---------------------------------------------------------------------------

extern "C" void kernel_launch(void* const* d_in, const int* in_sizes, int n_in,
                              void* d_out, int out_size, void* d_ws, size_t ws_size,
                              hipStream_t stream) {
    const float* x     = (const float*)d_in[0];
    const float* noise = (const float*)d_in[1];
    const int*   ei    = (const int*)d_in[2];
    const float* gamma = (const float*)d_in[3];
    const float* beta  = (const float*)d_in[4];
    const float* W1    = (const float*)d_in[5];
    const float* b1    = (const float*)d_in[6];
    const float* W2    = (const float*)d_in[7];
    const float* b2    = (const float*)d_in[8];
    const float* Wm    = (const float*)d_in[9];
    const float* bm    = (const float*)d_in[10];
    const float* Ws    = (const float*)d_in[11];
    const float* bs    = (const float*)d_in[12];

    const int N  = in_sizes[0] / 128;
    const int E  = in_sizes[2] / 2;
    const int NPAD = (N + 127) & ~127;
    const int nb = (N + SCAN_ELEMS - 1) / SCAN_ELEMS;
    const int EB = (E + 255) / 256;
    const int CB = (N * 32 + 255) / 256;

    auto align256 = [](size_t b) { return (b + 255) & ~(size_t)255; };
    char* p = (char*)d_ws;
    int* cnt      = (int*)p;  p += align256((size_t)N * 4);
    int* row_ptr  = (int*)p;  p += align256((size_t)(N + 1) * 4);
    int* edge_src = (int*)p;  p += align256((size_t)E * 4);
    int* slot     = (int*)p;  p += align256((size_t)E * 4);
    int* bsums    = (int*)p;  p += align256((size_t)nb * 4);
    float* dinv   = (float*)p; p += align256((size_t)NPAD * 4);
    float* stats  = (float*)p; p += align256(512 * 4);
    float* bnpart = (float*)p; p += align256((size_t)256 * BN_G * 4);
    unsigned short* Wp1 = (unsigned short*)p; p += align256(128 * 128 * 2);
    unsigned short* Wp2 = (unsigned short*)p; p += align256(128 * 384 * 2);
    unsigned short* Wpc = (unsigned short*)p; p += align256(128 * 256 * 2);
    unsigned short* xb16 = (unsigned short*)p; p += align256((size_t)NPAD * 128 * 2);
    unsigned short* n16  = (unsigned short*)p; p += align256((size_t)NPAD * 128 * 2);
    unsigned short* h16  = (unsigned short*)p; p += align256((size_t)NPAD * 128 * 2);

    float* scale = stats + 256;
    float* shift = stats + 384;

    float* dout = (float*)d_out;                       // N*128 fp32
    unsigned short* hs12 = (unsigned short*)d_out;     // hs2 scratch (bf16)
    float* zm = dout;                                  // [N*64]
    float* zs = dout + (size_t)N * 64;                 // [N*64]

    const int gblocks = NPAD / 64;
    const int nblocks16 = (N + 15) / 16;

    // --- fused setup DAG ---
    hipMemsetAsync(cnt, 0, (size_t)N * 4, stream);
    fused1<<<BN_G + EB, 256, 0, stream>>>((const float4*)x, bnpart, N, ei, cnt, slot, E);
    fused2<<<256 + nb, 256, 0, stream>>>((const float4*)bnpart, stats, cnt, row_ptr, bsums, N);
    fused3<<<1, 256, 0, stream>>>(bsums, nb, stats, gamma, beta, scale, shift, 1.0f / (float)N);
    fused4<<<(N + 255) / 256, 256, 0, stream>>>(row_ptr, bsums, cnt, dinv, N, E);
    fused5<<<EB + CB + 384, 256, 0, stream>>>(
        ei, row_ptr, slot, edge_src, E, EB,
        (const float4*)x, (const float4*)noise, scale, shift,
        (ushort4*)xb16, (ushort4*)n16, N * 32, CB,
        W1, Wp1, W2, Wp2, Wm, Ws, Wpc);

    // conv1 GEMM: hs1 -> h16
    gemm_mfma<1><<<gblocks, 256, 0, stream>>>(xb16, nullptr, nullptr, Wp1, dinv, h16);
    // conv2 fused: gather(h16)->h1 LDS ; gemm([xb,noise,h1]) -> hs2 (d_out)
    gather_gemm<2><<<gblocks, 256, 0, stream>>>(
        xb16, n16, (const uint4*)h16, dinv, row_ptr, edge_src, b1, Wp2, hs12, N);
    // conv3 fused: gather(hs2)->h2 LDS ; gemm([xb,h2]) -> tms (h16)
    gather_gemm<1><<<gblocks, 256, 0, stream>>>(
        xb16, nullptr, (const uint4*)hs12, dinv, row_ptr, edge_src, b2, Wpc, h16, N);
    // final gather -> zm, zs
    gather_dual<<<nblocks16, 256, 0, stream>>>((const uint4*)h16, dinv, row_ptr,
                                               edge_src, bm, bs, zm, zs, N);
}

// Round 17
// 277.069 us; speedup vs baseline: 1.0592x; 1.0592x over previous
//
#include <hip/hip_runtime.h>
#include <math.h>

// ---------------------------------------------------------------------------
// GCN encoder forward, bf16 MFMA formulation.  (r15 structure + count_deg ILP)
// Setup DAG fused into 5 mega-kernels:
//   memset(cnt) ; fused1 = bn_stats || count_deg(slot, 2 edges/thr)
//   fused2 = bn_reduce || scan_blocks ; fused3 = scan_bsums + bn_finalize
//   fused4 = scan_add + dinv ; fused5 = fill_edges || convert_inputs || pack_w
// Then: [gemm -> gather] x3. Gather: one 16-lane group per node.
// ---------------------------------------------------------------------------

typedef short bf16x8 __attribute__((ext_vector_type(8)));
typedef float f32x4 __attribute__((ext_vector_type(4)));
typedef float f32x2 __attribute__((ext_vector_type(2)));

#define BN_G 1024
#define SCAN_BLK 256
#define SCAN_ELEMS 1024

__device__ inline unsigned short f2bf(float f) {  // RNE
    unsigned int u = __builtin_bit_cast(unsigned int, f);
    u += 0x7fff + ((u >> 16) & 1);
    return (unsigned short)(u >> 16);
}
__device__ inline unsigned int pack2(float lo, float hi) {
    return ((unsigned int)f2bf(hi) << 16) | f2bf(lo);
}
__device__ inline f32x2 unp(unsigned int u) {
    return (f32x2){__builtin_bit_cast(float, u << 16),
                   __builtin_bit_cast(float, u & 0xffff0000u)};
}
__device__ inline void acc8v(f32x2* a, uint4 v) {   // vector adds -> v_pk_add_f32
    a[0] += unp(v.x); a[1] += unp(v.y); a[2] += unp(v.z); a[3] += unp(v.w);
}

__device__ __forceinline__ void gload_lds16(const void* g, void* l) {
    __builtin_amdgcn_global_load_lds(
        (const __attribute__((address_space(1))) unsigned int*)g,
        (__attribute__((address_space(3))) unsigned int*)l, 16, 0, 0);
}

// ---------------------------------------------------------------------------
// fused1: blocks [0,BN_G) = bn_stats ; [BN_G,+EB2) = count_deg 2 edges/thr
// ---------------------------------------------------------------------------
__global__ __launch_bounds__(256) void fused1(const float4* __restrict__ x4,
                                              float* __restrict__ partials, int n,
                                              const int* __restrict__ ei,
                                              int* __restrict__ cnt,
                                              int* __restrict__ slot, int E) {
    __shared__ float4 lds[2][8][32];
    int bid = blockIdx.x, t = threadIdx.x;
    if (bid < BN_G) {
        int cg = t & 31;
        int rs = t >> 5;
        float4 s = make_float4(0.f, 0.f, 0.f, 0.f);
        float4 q = make_float4(0.f, 0.f, 0.f, 0.f);
        const float4 z4 = make_float4(0.f, 0.f, 0.f, 0.f);
        const int stride = BN_G * 32;
        for (int r0 = bid * 32 + rs * 4; r0 < n; r0 += stride) {
            float4 v0 = x4[(size_t)r0 * 32 + cg];
            float4 v1 = (r0 + 1 < n) ? x4[(size_t)(r0 + 1) * 32 + cg] : z4;
            float4 v2 = (r0 + 2 < n) ? x4[(size_t)(r0 + 2) * 32 + cg] : z4;
            float4 v3 = (r0 + 3 < n) ? x4[(size_t)(r0 + 3) * 32 + cg] : z4;
            s.x += v0.x + v1.x + v2.x + v3.x;
            s.y += v0.y + v1.y + v2.y + v3.y;
            s.z += v0.z + v1.z + v2.z + v3.z;
            s.w += v0.w + v1.w + v2.w + v3.w;
            q.x = fmaf(v0.x, v0.x, fmaf(v1.x, v1.x, fmaf(v2.x, v2.x, fmaf(v3.x, v3.x, q.x))));
            q.y = fmaf(v0.y, v0.y, fmaf(v1.y, v1.y, fmaf(v2.y, v2.y, fmaf(v3.y, v3.y, q.y))));
            q.z = fmaf(v0.z, v0.z, fmaf(v1.z, v1.z, fmaf(v2.z, v2.z, fmaf(v3.z, v3.z, q.z))));
            q.w = fmaf(v0.w, v0.w, fmaf(v1.w, v1.w, fmaf(v2.w, v2.w, fmaf(v3.w, v3.w, q.w))));
        }
        lds[0][rs][cg] = s;
        lds[1][rs][cg] = q;
        __syncthreads();
        if (t < 64) {
            int which = t >> 5;
            int c = t & 31;
            float4 a = lds[which][0][c];
#pragma unroll
            for (int i = 1; i < 8; i++) {
                float4 b = lds[which][i][c];
                a.x += b.x; a.y += b.y; a.z += b.z; a.w += b.w;
            }
            int base = which * 128 + c * 4;
            partials[(size_t)(base + 0) * BN_G + bid] = a.x;
            partials[(size_t)(base + 1) * BN_G + bid] = a.y;
            partials[(size_t)(base + 2) * BN_G + bid] = a.z;
            partials[(size_t)(base + 3) * BN_G + bid] = a.w;
        }
        return;
    }
    int base = (bid - BN_G) * 512 + t;
    int e0 = base, e1 = base + 256;
    int d0 = (e0 < E) ? ei[E + e0] : 0;
    int d1 = (e1 < E) ? ei[E + e1] : 0;
    if (e0 < E) slot[e0] = atomicAdd(&cnt[d0], 1);
    if (e1 < E) slot[e1] = atomicAdd(&cnt[d1], 1);
}

// ---------------------------------------------------------------------------
// fused2: blocks [0,256) = bn_reduce ; [256, 256+nb) = scan_blocks
// ---------------------------------------------------------------------------
__global__ __launch_bounds__(256) void fused2(const float4* __restrict__ partials4,
                                              float* __restrict__ stats,
                                              const int* __restrict__ cnt,
                                              int* __restrict__ row_ptr,
                                              int* __restrict__ bsums, int n) {
    __shared__ float red[256];
    __shared__ int lds[SCAN_BLK];
    int t = threadIdx.x;
    if (blockIdx.x < 256) {
        int c = blockIdx.x;
        float4 v = partials4[(size_t)c * (BN_G / 4) + t];
        red[t] = v.x + v.y + v.z + v.w;
        __syncthreads();
        for (int off = 128; off > 0; off >>= 1) {
            if (t < off) red[t] += red[t + off];
            __syncthreads();
        }
        if (t == 0) stats[c] = red[0];
    } else {
        int blk = blockIdx.x - 256;
        int base = blk * SCAN_ELEMS;
        int v[4];
        int s = 0;
#pragma unroll
        for (int j = 0; j < 4; j++) {
            int i = base + t * 4 + j;
            v[j] = s;
            s += (i < n) ? cnt[i] : 0;
        }
        lds[t] = s;
        __syncthreads();
        for (int off = 1; off < SCAN_BLK; off <<= 1) {
            int val = (t >= off) ? lds[t - off] : 0;
            __syncthreads();
            lds[t] += val;
            __syncthreads();
        }
        int excl = (t == 0) ? 0 : lds[t - 1];
#pragma unroll
        for (int j = 0; j < 4; j++) {
            int i = base + t * 4 + j;
            if (i < n) row_ptr[i] = excl + v[j];
        }
        if (t == SCAN_BLK - 1) bsums[blk] = lds[t];
    }
}

// ---------------------------------------------------------------------------
// fused3 (1 block): t==0 serial-scans bsums ; t in [128,256) bn_finalize
// ---------------------------------------------------------------------------
__global__ void fused3(int* __restrict__ bsums, int nb,
                       const float* __restrict__ stats,
                       const float* __restrict__ gamma, const float* __restrict__ beta,
                       float* __restrict__ scale, float* __restrict__ shift, float invN) {
    int t = threadIdx.x;
    if (t == 0) {
        int acc = 0;
        for (int i = 0; i < nb; i++) { int c = bsums[i]; bsums[i] = acc; acc += c; }
    } else if (t >= 128 && t < 256) {
        int c = t - 128;
        float mu = stats[c] * invN;
        float var = stats[128 + c] * invN - mu * mu;
        float sc = gamma[c] / sqrtf(var + 1e-5f);
        scale[c] = sc;
        shift[c] = beta[c] - mu * sc;
    }
}

// ---------------------------------------------------------------------------
// fused4: scan_add + dinv in one pass over nodes
// ---------------------------------------------------------------------------
__global__ void fused4(int* __restrict__ row_ptr, const int* __restrict__ bsums,
                       const int* __restrict__ cnt, float* __restrict__ dinv,
                       int n, int E) {
    int i = blockIdx.x * blockDim.x + threadIdx.x;
    if (i < n) {
        row_ptr[i] += bsums[i / SCAN_ELEMS];
        dinv[i] = rsqrtf((float)cnt[i] + 1.0f);
    }
    if (i == 0) row_ptr[n] = E;
}

// ---------------------------------------------------------------------------
// pack W (fp32 [K][C], col slice at colOff) into MFMA fragment layout.
// ---------------------------------------------------------------------------
__device__ inline void pack_body(int i, const float* __restrict__ W,
                                 unsigned short* __restrict__ Wp,
                                 int K, int C, int colOff) {
    if (i >= K * C) return;
    int k = i / C, c = i % C;
    int gc = c + colOff;
    int s = k >> 7, kc = (k >> 5) & 3, lhi = (k >> 3) & 3, j = k & 7;
    int wc = gc >> 6, n = (gc >> 4) & 3, l15 = gc & 15;
    int lane = lhi * 16 + l15;
    size_t dst = ((size_t)((s * 2 + wc) * 4 + kc) * 4 + n) * 512 + lane * 8 + j;
    Wp[dst] = f2bf(W[i]);
}

// ---------------------------------------------------------------------------
// fused5: fill_edges || convert_inputs (x and noise) || pack_w x4
// ---------------------------------------------------------------------------
__global__ __launch_bounds__(256) void fused5(
    const int* __restrict__ ei, const int* __restrict__ row_ptr,
    const int* __restrict__ slot, int* __restrict__ edge_src, int E, int EB,
    const float4* __restrict__ x4, const float4* __restrict__ n4,
    const float* __restrict__ scale, const float* __restrict__ shift,
    ushort4* __restrict__ xb, ushort4* __restrict__ nb4, int total4, int CB,
    const float* __restrict__ W1, unsigned short* __restrict__ Wp1,
    const float* __restrict__ W2, unsigned short* __restrict__ Wp2,
    const float* __restrict__ Wm, const float* __restrict__ Ws,
    unsigned short* __restrict__ Wpc)
{
    int bid = blockIdx.x, t = threadIdx.x;
    if (bid < EB) {
        int e = bid * 256 + t;
        if (e < E) {
            int s = ei[e], d = ei[E + e];
            edge_src[row_ptr[d] + slot[e]] = s;
        }
        return;
    }
    bid -= EB;
    if (bid < CB) {
        int i = bid * 256 + t;
        if (i < total4) {
            int c4 = (i & 31) << 2;
            float4 sc = *reinterpret_cast<const float4*>(scale + c4);
            float4 sh = *reinterpret_cast<const float4*>(shift + c4);
            float4 v = x4[i];
            ushort4 o;
            o.x = f2bf(fmaf(v.x, sc.x, sh.x));
            o.y = f2bf(fmaf(v.y, sc.y, sh.y));
            o.z = f2bf(fmaf(v.z, sc.z, sh.z));
            o.w = f2bf(fmaf(v.w, sc.w, sh.w));
            xb[i] = o;
            float4 w = n4[i];
            ushort4 p;
            p.x = f2bf(w.x); p.y = f2bf(w.y); p.z = f2bf(w.z); p.w = f2bf(w.w);
            nb4[i] = p;
        }
        return;
    }
    bid -= CB;
    if (bid < 64)  { pack_body(bid * 256 + t, W1, Wp1, 128, 128, 0); return; }
    bid -= 64;
    if (bid < 192) { pack_body(bid * 256 + t, W2, Wp2, 384, 128, 0); return; }
    bid -= 192;
    if (bid < 64)  { pack_body(bid * 256 + t, Wm, Wpc, 256, 64, 0); return; }
    bid -= 64;
    pack_body(bid * 256 + t, Ws, Wpc, 256, 64, 64);
}

// ---------------------------------------------------------------------------
// MFMA GEMM: hs[MP x 128] = (sum_s A_s[MP x 128] @ W[s*128:, :]) * dinv[row]
// ---------------------------------------------------------------------------
template <int NSRC>
__global__ __launch_bounds__(256, 4) void gemm_mfma(
    const unsigned short* __restrict__ A0, const unsigned short* __restrict__ A1,
    const unsigned short* __restrict__ A2,
    const unsigned short* __restrict__ Wpk,  // packed fragments
    const float* __restrict__ dinv, unsigned short* __restrict__ out)
{
    constexpr int NBUF = (NSRC > 1) ? 2 : 1;
    __shared__ unsigned char ldsA[NBUF][64 * 256];

    const int lane = threadIdx.x & 63;
    const int wid  = threadIdx.x >> 6;
    const int wr   = wid >> 1, wc = wid & 1;
    const int l15  = lane & 15, lhi = lane >> 4;
    const int c0   = wc * 64;
    const long rowblk = (long)blockIdx.x * 64;
    const int rl0 = wr * 32 + l15;
    const int rl1 = rl0 + 16;
    const int rsw = rl0 & 7;

    const unsigned short* __restrict__ srcs[3] = {A0, A1, A2};
    auto stage = [&](int s, int b) {
#pragma unroll
        for (int i = 0; i < 4; i++) {
            int G = (wid * 4 + i) * 64 + lane;
            int r = G >> 4, g = G & 15;
            const unsigned short* src = srcs[s] + (rowblk + r) * 128 + (g ^ (r & 7)) * 8;
            gload_lds16(src, &ldsA[b][G * 16]);
        }
    };

    f32x4 acc[2][4];
#pragma unroll
    for (int g = 0; g < 2; g++)
#pragma unroll
        for (int n = 0; n < 4; n++)
            acc[g][n] = (f32x4){0.f, 0.f, 0.f, 0.f};

    stage(0, 0);

#pragma unroll
    for (int s = 0; s < NSRC; s++) {
        const unsigned short* wbase = Wpk + ((size_t)(s * 2 + wc) * 16) * 512 + lane * 8;
        bf16x8 w[4][4];
#pragma unroll
        for (int kc = 0; kc < 4; kc++)
#pragma unroll
            for (int n = 0; n < 4; n++)
                w[kc][n] = *reinterpret_cast<const bf16x8*>(wbase + (kc * 4 + n) * 512);

        __syncthreads();                         // stage(s) + W(s) complete
        if (s + 1 < NSRC) stage(s + 1, (s + 1) % NBUF);
        const unsigned char* bufp = ldsA[s % NBUF];

#pragma unroll
        for (int kc = 0; kc < 4; kc++) {
            int g0 = kc * 4 + lhi;
            bf16x8 a0 = *reinterpret_cast<const bf16x8*>(bufp + rl0 * 256 + (g0 ^ rsw) * 16);
            bf16x8 a1 = *reinterpret_cast<const bf16x8*>(bufp + rl1 * 256 + (g0 ^ rsw) * 16);
#pragma unroll
            for (int n = 0; n < 4; n++) {
                acc[0][n] = __builtin_amdgcn_mfma_f32_16x16x32_bf16(w[kc][n], a0, acc[0][n], 0, 0, 0);
                acc[1][n] = __builtin_amdgcn_mfma_f32_16x16x32_bf16(w[kc][n], a1, acc[1][n], 0, 0, 0);
            }
        }
    }

#pragma unroll
    for (int g = 0; g < 2; g++) {
        long row = rowblk + (g ? rl1 : rl0);
        float dv = dinv[row];
        unsigned short* op = out + row * 128 + c0 + lhi * 4;
#pragma unroll
        for (int n = 0; n < 4; n++) {
            f32x4 v = acc[g][n];
            ushort4 pk;
            pk.x = f2bf(v[0] * dv);
            pk.y = f2bf(v[1] * dv);
            pk.z = f2bf(v[2] * dv);
            pk.w = f2bf(v[3] * dv);
            *reinterpret_cast<ushort4*>(op + n * 16) = pk;
        }
    }
}

// ---------------------------------------------------------------------------
// CSR gather: one 16-lane group per node (16 nodes / 256-thr block).
// Each lane owns 16B of the 256B row; group walks its node's edge list with
// a 4-deep unrolled dual-accumulator loop. No cross-lane reduce.
// ---------------------------------------------------------------------------
template <bool RELU>
__global__ void gather16(const uint4* __restrict__ hs4, const float* __restrict__ dinv,
                         const int* __restrict__ row_ptr, const int* __restrict__ edge_src,
                         const float* __restrict__ bias, uint4* __restrict__ out4, int n) {
    int node = blockIdx.x * 16 + (threadIdx.x >> 4);
    if (node >= n) return;
    int cl = threadIdx.x & 15;
    int beg = row_ptr[node], end = row_ptr[node + 1];
    f32x2 a[4] = {(f32x2){0.f,0.f}, (f32x2){0.f,0.f}, (f32x2){0.f,0.f}, (f32x2){0.f,0.f}};
    f32x2 b[4] = {(f32x2){0.f,0.f}, (f32x2){0.f,0.f}, (f32x2){0.f,0.f}, (f32x2){0.f,0.f}};
    acc8v(a, hs4[(size_t)node * 16 + cl]);   // self-loop
    int e = beg;
    for (; e + 4 <= end; e += 4) {
        uint4 v0 = hs4[(size_t)edge_src[e] * 16 + cl];
        uint4 v1 = hs4[(size_t)edge_src[e + 1] * 16 + cl];
        uint4 v2 = hs4[(size_t)edge_src[e + 2] * 16 + cl];
        uint4 v3 = hs4[(size_t)edge_src[e + 3] * 16 + cl];
        acc8v(a, v0);
        acc8v(b, v1);
        acc8v(a, v2);
        acc8v(b, v3);
    }
    if (e + 2 <= end) {
        uint4 v0 = hs4[(size_t)edge_src[e] * 16 + cl];
        uint4 v1 = hs4[(size_t)edge_src[e + 1] * 16 + cl];
        acc8v(a, v0);
        acc8v(b, v1);
        e += 2;
    }
    if (e < end) acc8v(a, hs4[(size_t)edge_src[e] * 16 + cl]);
#pragma unroll
    for (int i = 0; i < 4; i++) a[i] += b[i];
    float dv = dinv[node];
    float4 b0 = *reinterpret_cast<const float4*>(bias + cl * 8);
    float4 b1 = *reinterpret_cast<const float4*>(bias + cl * 8 + 4);
    float r0 = fmaf(a[0].x, dv, b0.x), r1 = fmaf(a[0].y, dv, b0.y);
    float r2 = fmaf(a[1].x, dv, b0.z), r3 = fmaf(a[1].y, dv, b0.w);
    float r4 = fmaf(a[2].x, dv, b1.x), r5 = fmaf(a[2].y, dv, b1.y);
    float r6 = fmaf(a[3].x, dv, b1.z), r7 = fmaf(a[3].y, dv, b1.w);
    if (RELU) {
        r0 = fmaxf(r0, 0.f); r1 = fmaxf(r1, 0.f); r2 = fmaxf(r2, 0.f); r3 = fmaxf(r3, 0.f);
        r4 = fmaxf(r4, 0.f); r5 = fmaxf(r5, 0.f); r6 = fmaxf(r6, 0.f); r7 = fmaxf(r7, 0.f);
    }
    uint4 o;
    o.x = pack2(r0, r1); o.y = pack2(r2, r3);
    o.z = pack2(r4, r5); o.w = pack2(r6, r7);
    out4[(size_t)node * 16 + cl] = o;
}

// final: t rows = [tm(64) | ts(64)] bf16 -> zm, zs fp32
__global__ void gather_dual(const uint4* __restrict__ hs4, const float* __restrict__ dinv,
                            const int* __restrict__ row_ptr, const int* __restrict__ edge_src,
                            const float* __restrict__ bm, const float* __restrict__ bs,
                            float* __restrict__ zm, float* __restrict__ zs, int n) {
    int node = blockIdx.x * 16 + (threadIdx.x >> 4);
    if (node >= n) return;
    int cl = threadIdx.x & 15;
    int beg = row_ptr[node], end = row_ptr[node + 1];
    f32x2 a[4] = {(f32x2){0.f,0.f}, (f32x2){0.f,0.f}, (f32x2){0.f,0.f}, (f32x2){0.f,0.f}};
    f32x2 b[4] = {(f32x2){0.f,0.f}, (f32x2){0.f,0.f}, (f32x2){0.f,0.f}, (f32x2){0.f,0.f}};
    acc8v(a, hs4[(size_t)node * 16 + cl]);
    int e = beg;
    for (; e + 4 <= end; e += 4) {
        uint4 v0 = hs4[(size_t)edge_src[e] * 16 + cl];
        uint4 v1 = hs4[(size_t)edge_src[e + 1] * 16 + cl];
        uint4 v2 = hs4[(size_t)edge_src[e + 2] * 16 + cl];
        uint4 v3 = hs4[(size_t)edge_src[e + 3] * 16 + cl];
        acc8v(a, v0);
        acc8v(b, v1);
        acc8v(a, v2);
        acc8v(b, v3);
    }
    if (e + 2 <= end) {
        uint4 v0 = hs4[(size_t)edge_src[e] * 16 + cl];
        uint4 v1 = hs4[(size_t)edge_src[e + 1] * 16 + cl];
        acc8v(a, v0);
        acc8v(b, v1);
        e += 2;
    }
    if (e < end) acc8v(a, hs4[(size_t)edge_src[e] * 16 + cl]);
#pragma unroll
    for (int i = 0; i < 4; i++) a[i] += b[i];
    float dv = dinv[node];
    const float* bp = (cl < 8) ? (bm + cl * 8) : (bs + (cl - 8) * 8);
    float* zp = (cl < 8) ? (zm + (size_t)node * 64 + cl * 8)
                         : (zs + (size_t)node * 64 + (cl - 8) * 8);
    float4 b0 = *reinterpret_cast<const float4*>(bp);
    float4 b1 = *reinterpret_cast<const float4*>(bp + 4);
    float4 o0 = make_float4(fmaf(a[0].x, dv, b0.x), fmaf(a[0].y, dv, b0.y),
                            fmaf(a[1].x, dv, b0.z), fmaf(a[1].y, dv, b0.w));
    float4 o1 = make_float4(fmaf(a[2].x, dv, b1.x), fmaf(a[2].y, dv, b1.y),
                            fmaf(a[3].x, dv, b1.z), fmaf(a[3].y, dv, b1.w));
    *reinterpret_cast<float4*>(zp) = o0;
    *reinterpret_cast<float4*>(zp + 4) = o1;
}

// ---------------------------------------------------------------------------

extern "C" void kernel_launch(void* const* d_in, const int* in_sizes, int n_in,
                              void* d_out, int out_size, void* d_ws, size_t ws_size,
                              hipStream_t stream) {
    const float* x     = (const float*)d_in[0];
    const float* noise = (const float*)d_in[1];
    const int*   ei    = (const int*)d_in[2];
    const float* gamma = (const float*)d_in[3];
    const float* beta  = (const float*)d_in[4];
    const float* W1    = (const float*)d_in[5];
    const float* b1    = (const float*)d_in[6];
    const float* W2    = (const float*)d_in[7];
    const float* b2    = (const float*)d_in[8];
    const float* Wm    = (const float*)d_in[9];
    const float* bm    = (const float*)d_in[10];
    const float* Ws    = (const float*)d_in[11];
    const float* bs    = (const float*)d_in[12];

    const int N  = in_sizes[0] / 128;
    const int E  = in_sizes[2] / 2;
    const int NPAD = (N + 127) & ~127;
    const int nb = (N + SCAN_ELEMS - 1) / SCAN_ELEMS;
    const int EB  = (E + 255) / 256;
    const int EB2 = (E + 511) / 512;
    const int CB  = (N * 32 + 255) / 256;

    auto align256 = [](size_t b) { return (b + 255) & ~(size_t)255; };
    char* p = (char*)d_ws;
    int* cnt      = (int*)p;  p += align256((size_t)N * 4);
    int* row_ptr  = (int*)p;  p += align256((size_t)(N + 1) * 4);
    int* edge_src = (int*)p;  p += align256((size_t)E * 4);
    int* slot     = (int*)p;  p += align256((size_t)E * 4);
    int* bsums    = (int*)p;  p += align256((size_t)nb * 4);
    float* dinv   = (float*)p; p += align256((size_t)NPAD * 4);
    float* stats  = (float*)p; p += align256(512 * 4);
    float* bnpart = (float*)p; p += align256((size_t)256 * BN_G * 4);
    unsigned short* Wp1 = (unsigned short*)p; p += align256(128 * 128 * 2);
    unsigned short* Wp2 = (unsigned short*)p; p += align256(128 * 384 * 2);
    unsigned short* Wpc = (unsigned short*)p; p += align256(128 * 256 * 2);
    unsigned short* xb16 = (unsigned short*)p; p += align256((size_t)NPAD * 128 * 2);
    unsigned short* n16  = (unsigned short*)p; p += align256((size_t)NPAD * 128 * 2);
    unsigned short* h16  = (unsigned short*)p; p += align256((size_t)NPAD * 128 * 2);

    float* scale = stats + 256;
    float* shift = stats + 384;

    float* dout = (float*)d_out;                       // N*128 fp32
    unsigned short* hs12 = (unsigned short*)d_out;     // conv1/2 hs scratch
    unsigned short* hs3  = n16;                        // noise dead after conv2
    float* zm = dout;                                  // [N*64]
    float* zs = dout + (size_t)N * 64;                 // [N*64]

    const int gblocks = NPAD / 64;
    const int nblocks16 = (N + 15) / 16;

    // --- fused setup DAG ---
    hipMemsetAsync(cnt, 0, (size_t)N * 4, stream);
    fused1<<<BN_G + EB2, 256, 0, stream>>>((const float4*)x, bnpart, N, ei, cnt, slot, E);
    fused2<<<256 + nb, 256, 0, stream>>>((const float4*)bnpart, stats, cnt, row_ptr, bsums, N);
    fused3<<<1, 256, 0, stream>>>(bsums, nb, stats, gamma, beta, scale, shift, 1.0f / (float)N);
    fused4<<<(N + 255) / 256, 256, 0, stream>>>(row_ptr, bsums, cnt, dinv, N, E);
    fused5<<<EB + CB + 384, 256, 0, stream>>>(
        ei, row_ptr, slot, edge_src, E, EB,
        (const float4*)x, (const float4*)noise, scale, shift,
        (ushort4*)xb16, (ushort4*)n16, N * 32, CB,
        W1, Wp1, W2, Wp2, Wm, Ws, Wpc);

    // conv1
    gemm_mfma<1><<<gblocks, 256, 0, stream>>>(xb16, nullptr, nullptr, Wp1, dinv, hs12);
    gather16<true><<<nblocks16, 256, 0, stream>>>((const uint4*)hs12, dinv, row_ptr,
                                                  edge_src, b1, (uint4*)h16, N);
    // conv2
    gemm_mfma<3><<<gblocks, 256, 0, stream>>>(xb16, n16, h16, Wp2, dinv, hs12);
    gather16<true><<<nblocks16, 256, 0, stream>>>((const uint4*)hs12, dinv, row_ptr,
                                                  edge_src, b2, (uint4*)h16, N);
    // mean/logstd fused
    gemm_mfma<2><<<gblocks, 256, 0, stream>>>(xb16, h16, nullptr, Wpc, dinv, hs3);
    gather_dual<<<nblocks16, 256, 0, stream>>>((const uint4*)hs3, dinv, row_ptr,
                                               edge_src, bm, bs, zm, zs, N);
}

// Round 18
// 270.910 us; speedup vs baseline: 1.0833x; 1.0227x over previous
//
#include <hip/hip_runtime.h>
#include <math.h>

// ---------------------------------------------------------------------------
// GCN encoder forward, bf16 MFMA formulation, BN folded into weights:
//   xb@W = x@(diag(scale)W) + shift@W  =>  never materialize xb.
//   fused1 = bn_stats (also writes x16 = bf16(x)) || count_deg(slot)
//   fused2 = bn_reduce || scan_blocks ; fused3 = scan_bsums + bn_finalize
//   fused4 = scan_add + dinv
//   fused5 = fill_edges || noise->bf16 || pack_w(scale-folded) x4 || cvec x3
//   [gemm(+cvec epilogue) -> gather] x3 ; gather: 16-lane group per node.
// ---------------------------------------------------------------------------

typedef short bf16x8 __attribute__((ext_vector_type(8)));
typedef float f32x4 __attribute__((ext_vector_type(4)));
typedef float f32x2 __attribute__((ext_vector_type(2)));

#define BN_G 1024
#define SCAN_BLK 256
#define SCAN_ELEMS 1024

__device__ inline unsigned short f2bf(float f) {  // RNE
    unsigned int u = __builtin_bit_cast(unsigned int, f);
    u += 0x7fff + ((u >> 16) & 1);
    return (unsigned short)(u >> 16);
}
__device__ inline unsigned int pack2(float lo, float hi) {
    return ((unsigned int)f2bf(hi) << 16) | f2bf(lo);
}
__device__ inline f32x2 unp(unsigned int u) {
    return (f32x2){__builtin_bit_cast(float, u << 16),
                   __builtin_bit_cast(float, u & 0xffff0000u)};
}
__device__ inline void acc8v(f32x2* a, uint4 v) {   // vector adds -> v_pk_add_f32
    a[0] += unp(v.x); a[1] += unp(v.y); a[2] += unp(v.z); a[3] += unp(v.w);
}
__device__ inline ushort4 cvt4(float4 v) {
    ushort4 o;
    o.x = f2bf(v.x); o.y = f2bf(v.y); o.z = f2bf(v.z); o.w = f2bf(v.w);
    return o;
}

__device__ __forceinline__ void gload_lds16(const void* g, void* l) {
    __builtin_amdgcn_global_load_lds(
        (const __attribute__((address_space(1))) unsigned int*)g,
        (__attribute__((address_space(3))) unsigned int*)l, 16, 0, 0);
}

// ---------------------------------------------------------------------------
// fused1: blocks [0,BN_G) = bn_stats + x16 write ; [BN_G,+EB) = count_deg
// ---------------------------------------------------------------------------
__global__ __launch_bounds__(256) void fused1(const float4* __restrict__ x4,
                                              float* __restrict__ partials, int n,
                                              ushort4* __restrict__ x16,
                                              const int* __restrict__ ei,
                                              int* __restrict__ cnt,
                                              int* __restrict__ slot, int E) {
    __shared__ float4 lds[2][8][32];
    int bid = blockIdx.x, t = threadIdx.x;
    if (bid < BN_G) {
        int cg = t & 31;
        int rs = t >> 5;
        float4 s = make_float4(0.f, 0.f, 0.f, 0.f);
        float4 q = make_float4(0.f, 0.f, 0.f, 0.f);
        const float4 z4 = make_float4(0.f, 0.f, 0.f, 0.f);
        const int stride = BN_G * 32;
        for (int r0 = bid * 32 + rs * 4; r0 < n; r0 += stride) {
            float4 v0 = x4[(size_t)r0 * 32 + cg];
            float4 v1 = (r0 + 1 < n) ? x4[(size_t)(r0 + 1) * 32 + cg] : z4;
            float4 v2 = (r0 + 2 < n) ? x4[(size_t)(r0 + 2) * 32 + cg] : z4;
            float4 v3 = (r0 + 3 < n) ? x4[(size_t)(r0 + 3) * 32 + cg] : z4;
            x16[(size_t)r0 * 32 + cg] = cvt4(v0);
            if (r0 + 1 < n) x16[(size_t)(r0 + 1) * 32 + cg] = cvt4(v1);
            if (r0 + 2 < n) x16[(size_t)(r0 + 2) * 32 + cg] = cvt4(v2);
            if (r0 + 3 < n) x16[(size_t)(r0 + 3) * 32 + cg] = cvt4(v3);
            s.x += v0.x + v1.x + v2.x + v3.x;
            s.y += v0.y + v1.y + v2.y + v3.y;
            s.z += v0.z + v1.z + v2.z + v3.z;
            s.w += v0.w + v1.w + v2.w + v3.w;
            q.x = fmaf(v0.x, v0.x, fmaf(v1.x, v1.x, fmaf(v2.x, v2.x, fmaf(v3.x, v3.x, q.x))));
            q.y = fmaf(v0.y, v0.y, fmaf(v1.y, v1.y, fmaf(v2.y, v2.y, fmaf(v3.y, v3.y, q.y))));
            q.z = fmaf(v0.z, v0.z, fmaf(v1.z, v1.z, fmaf(v2.z, v2.z, fmaf(v3.z, v3.z, q.z))));
            q.w = fmaf(v0.w, v0.w, fmaf(v1.w, v1.w, fmaf(v2.w, v2.w, fmaf(v3.w, v3.w, q.w))));
        }
        lds[0][rs][cg] = s;
        lds[1][rs][cg] = q;
        __syncthreads();
        if (t < 64) {
            int which = t >> 5;
            int c = t & 31;
            float4 a = lds[which][0][c];
#pragma unroll
            for (int i = 1; i < 8; i++) {
                float4 b = lds[which][i][c];
                a.x += b.x; a.y += b.y; a.z += b.z; a.w += b.w;
            }
            int base = which * 128 + c * 4;
            partials[(size_t)(base + 0) * BN_G + bid] = a.x;
            partials[(size_t)(base + 1) * BN_G + bid] = a.y;
            partials[(size_t)(base + 2) * BN_G + bid] = a.z;
            partials[(size_t)(base + 3) * BN_G + bid] = a.w;
        }
        return;
    }
    int e = (bid - BN_G) * 256 + t;
    if (e < E) slot[e] = atomicAdd(&cnt[ei[E + e]], 1);
}

// ---------------------------------------------------------------------------
// fused2: blocks [0,256) = bn_reduce ; [256, 256+nb) = scan_blocks
// ---------------------------------------------------------------------------
__global__ __launch_bounds__(256) void fused2(const float4* __restrict__ partials4,
                                              float* __restrict__ stats,
                                              const int* __restrict__ cnt,
                                              int* __restrict__ row_ptr,
                                              int* __restrict__ bsums, int n) {
    __shared__ float red[256];
    __shared__ int lds[SCAN_BLK];
    int t = threadIdx.x;
    if (blockIdx.x < 256) {
        int c = blockIdx.x;
        float4 v = partials4[(size_t)c * (BN_G / 4) + t];
        red[t] = v.x + v.y + v.z + v.w;
        __syncthreads();
        for (int off = 128; off > 0; off >>= 1) {
            if (t < off) red[t] += red[t + off];
            __syncthreads();
        }
        if (t == 0) stats[c] = red[0];
    } else {
        int blk = blockIdx.x - 256;
        int base = blk * SCAN_ELEMS;
        int v[4];
        int s = 0;
#pragma unroll
        for (int j = 0; j < 4; j++) {
            int i = base + t * 4 + j;
            v[j] = s;
            s += (i < n) ? cnt[i] : 0;
        }
        lds[t] = s;
        __syncthreads();
        for (int off = 1; off < SCAN_BLK; off <<= 1) {
            int val = (t >= off) ? lds[t - off] : 0;
            __syncthreads();
            lds[t] += val;
            __syncthreads();
        }
        int excl = (t == 0) ? 0 : lds[t - 1];
#pragma unroll
        for (int j = 0; j < 4; j++) {
            int i = base + t * 4 + j;
            if (i < n) row_ptr[i] = excl + v[j];
        }
        if (t == SCAN_BLK - 1) bsums[blk] = lds[t];
    }
}

// ---------------------------------------------------------------------------
// fused3 (1 block): t==0 serial-scans bsums ; t in [128,256) bn_finalize
// ---------------------------------------------------------------------------
__global__ void fused3(int* __restrict__ bsums, int nb,
                       const float* __restrict__ stats,
                       const float* __restrict__ gamma, const float* __restrict__ beta,
                       float* __restrict__ scale, float* __restrict__ shift, float invN) {
    int t = threadIdx.x;
    if (t == 0) {
        int acc = 0;
        for (int i = 0; i < nb; i++) { int c = bsums[i]; bsums[i] = acc; acc += c; }
    } else if (t >= 128 && t < 256) {
        int c = t - 128;
        float mu = stats[c] * invN;
        float var = stats[128 + c] * invN - mu * mu;
        float sc = gamma[c] / sqrtf(var + 1e-5f);
        scale[c] = sc;
        shift[c] = beta[c] - mu * sc;
    }
}

// ---------------------------------------------------------------------------
// fused4: scan_add + dinv in one pass over nodes
// ---------------------------------------------------------------------------
__global__ void fused4(int* __restrict__ row_ptr, const int* __restrict__ bsums,
                       const int* __restrict__ cnt, float* __restrict__ dinv,
                       int n, int E) {
    int i = blockIdx.x * blockDim.x + threadIdx.x;
    if (i < n) {
        row_ptr[i] += bsums[i / SCAN_ELEMS];
        dinv[i] = rsqrtf((float)cnt[i] + 1.0f);
    }
    if (i == 0) row_ptr[n] = E;
}

// ---------------------------------------------------------------------------
// pack W (fp32 [K][C], col slice at colOff) into MFMA fragment layout.
// Rows k<128 (the xb source) are scaled by scale[k] (BN fold).
// ---------------------------------------------------------------------------
__device__ inline void pack_body(int i, const float* __restrict__ W,
                                 unsigned short* __restrict__ Wp,
                                 int K, int C, int colOff,
                                 const float* __restrict__ scale) {
    if (i >= K * C) return;
    int k = i / C, c = i % C;
    float v = W[i];
    if (k < 128) v *= scale[k];
    int gc = c + colOff;
    int s = k >> 7, kc = (k >> 5) & 3, lhi = (k >> 3) & 3, j = k & 7;
    int wc = gc >> 6, n = (gc >> 4) & 3, l15 = gc & 15;
    int lane = lhi * 16 + l15;
    size_t dst = ((size_t)((s * 2 + wc) * 4 + kc) * 4 + n) * 512 + lane * 8 + j;
    Wp[dst] = f2bf(v);
}

// ---------------------------------------------------------------------------
// fused5: fill_edges || noise->bf16 || pack_w x4 || cvec x3
// cvec[c] = sum_{k<128} shift[k] * W[k][c]
// ---------------------------------------------------------------------------
__global__ __launch_bounds__(256) void fused5(
    const int* __restrict__ ei, const int* __restrict__ row_ptr,
    const int* __restrict__ slot, int* __restrict__ edge_src, int E, int EB,
    const float4* __restrict__ n4, ushort4* __restrict__ nb4, int total4, int CB,
    const float* __restrict__ scale, const float* __restrict__ shift,
    const float* __restrict__ W1, unsigned short* __restrict__ Wp1,
    const float* __restrict__ W2, unsigned short* __restrict__ Wp2,
    const float* __restrict__ Wm, const float* __restrict__ Ws,
    unsigned short* __restrict__ Wpc,
    float* __restrict__ cv1, float* __restrict__ cv2, float* __restrict__ cvc)
{
    __shared__ float cred[256];
    int bid = blockIdx.x, t = threadIdx.x;
    if (bid < EB) {
        int e = bid * 256 + t;
        if (e < E) {
            int s = ei[e], d = ei[E + e];
            edge_src[row_ptr[d] + slot[e]] = s;
        }
        return;
    }
    bid -= EB;
    if (bid < CB) {
        int i = bid * 256 + t;
        if (i < total4) nb4[i] = cvt4(n4[i]);
        return;
    }
    bid -= CB;
    if (bid < 64)  { pack_body(bid * 256 + t, W1, Wp1, 128, 128, 0, scale); return; }
    bid -= 64;
    if (bid < 192) { pack_body(bid * 256 + t, W2, Wp2, 384, 128, 0, scale); return; }
    bid -= 192;
    if (bid < 64)  { pack_body(bid * 256 + t, Wm, Wpc, 256, 64, 0, scale); return; }
    bid -= 64;
    if (bid < 64)  { pack_body(bid * 256 + t, Ws, Wpc, 256, 64, 64, scale); return; }
    bid -= 64;
    // cvec blocks: bid in [0,3). c = t&127, kh = t>>7 covers k range kh*64..+64
    {
        int c = t & 127, kh = t >> 7;
        float s = 0.f;
        if (bid == 0) {
            for (int k = kh * 64; k < kh * 64 + 64; k++)
                s = fmaf(shift[k], W1[k * 128 + c], s);
        } else if (bid == 1) {
            for (int k = kh * 64; k < kh * 64 + 64; k++)
                s = fmaf(shift[k], W2[k * 128 + c], s);
        } else {
            const float* Wsrc = (c < 64) ? Wm : Ws;
            int cc = (c < 64) ? c : c - 64;
            for (int k = kh * 64; k < kh * 64 + 64; k++)
                s = fmaf(shift[k], Wsrc[k * 64 + cc], s);
        }
        cred[t] = s;
        __syncthreads();
        if (t < 128) {
            float v = cred[t] + cred[t + 128];
            float* dst = (bid == 0) ? cv1 : (bid == 1) ? cv2 : cvc;
            dst[c] = v;
        }
    }
}

// ---------------------------------------------------------------------------
// MFMA GEMM: out[r][c] = (sum_s A_s@W_s + cvec[c]) * dinv[r], bf16 out
// ---------------------------------------------------------------------------
template <int NSRC>
__global__ __launch_bounds__(256, 4) void gemm_mfma(
    const unsigned short* __restrict__ A0, const unsigned short* __restrict__ A1,
    const unsigned short* __restrict__ A2,
    const unsigned short* __restrict__ Wpk,  // packed fragments
    const float* __restrict__ dinv, const float* __restrict__ cvec,
    unsigned short* __restrict__ out)
{
    constexpr int NBUF = (NSRC > 1) ? 2 : 1;
    __shared__ unsigned char ldsA[NBUF][64 * 256];

    const int lane = threadIdx.x & 63;
    const int wid  = threadIdx.x >> 6;
    const int wr   = wid >> 1, wc = wid & 1;
    const int l15  = lane & 15, lhi = lane >> 4;
    const int c0   = wc * 64;
    const long rowblk = (long)blockIdx.x * 64;
    const int rl0 = wr * 32 + l15;
    const int rl1 = rl0 + 16;
    const int rsw = rl0 & 7;

    const unsigned short* __restrict__ srcs[3] = {A0, A1, A2};
    auto stage = [&](int s, int b) {
#pragma unroll
        for (int i = 0; i < 4; i++) {
            int G = (wid * 4 + i) * 64 + lane;
            int r = G >> 4, g = G & 15;
            const unsigned short* src = srcs[s] + (rowblk + r) * 128 + (g ^ (r & 7)) * 8;
            gload_lds16(src, &ldsA[b][G * 16]);
        }
    };

    f32x4 acc[2][4];
#pragma unroll
    for (int g = 0; g < 2; g++)
#pragma unroll
        for (int n = 0; n < 4; n++)
            acc[g][n] = (f32x4){0.f, 0.f, 0.f, 0.f};

    stage(0, 0);

#pragma unroll
    for (int s = 0; s < NSRC; s++) {
        const unsigned short* wbase = Wpk + ((size_t)(s * 2 + wc) * 16) * 512 + lane * 8;
        bf16x8 w[4][4];
#pragma unroll
        for (int kc = 0; kc < 4; kc++)
#pragma unroll
            for (int n = 0; n < 4; n++)
                w[kc][n] = *reinterpret_cast<const bf16x8*>(wbase + (kc * 4 + n) * 512);

        __syncthreads();                         // stage(s) + W(s) complete
        if (s + 1 < NSRC) stage(s + 1, (s + 1) % NBUF);
        const unsigned char* bufp = ldsA[s % NBUF];

#pragma unroll
        for (int kc = 0; kc < 4; kc++) {
            int g0 = kc * 4 + lhi;
            bf16x8 a0 = *reinterpret_cast<const bf16x8*>(bufp + rl0 * 256 + (g0 ^ rsw) * 16);
            bf16x8 a1 = *reinterpret_cast<const bf16x8*>(bufp + rl1 * 256 + (g0 ^ rsw) * 16);
#pragma unroll
            for (int n = 0; n < 4; n++) {
                acc[0][n] = __builtin_amdgcn_mfma_f32_16x16x32_bf16(w[kc][n], a0, acc[0][n], 0, 0, 0);
                acc[1][n] = __builtin_amdgcn_mfma_f32_16x16x32_bf16(w[kc][n], a1, acc[1][n], 0, 0, 0);
            }
        }
    }

    float4 cv[4];
#pragma unroll
    for (int n = 0; n < 4; n++)
        cv[n] = *reinterpret_cast<const float4*>(cvec + c0 + n * 16 + lhi * 4);

#pragma unroll
    for (int g = 0; g < 2; g++) {
        long row = rowblk + (g ? rl1 : rl0);
        float dv = dinv[row];
        unsigned short* op = out + row * 128 + c0 + lhi * 4;
#pragma unroll
        for (int n = 0; n < 4; n++) {
            f32x4 v = acc[g][n];
            ushort4 pk;
            pk.x = f2bf((v[0] + cv[n].x) * dv);
            pk.y = f2bf((v[1] + cv[n].y) * dv);
            pk.z = f2bf((v[2] + cv[n].z) * dv);
            pk.w = f2bf((v[3] + cv[n].w) * dv);
            *reinterpret_cast<ushort4*>(op + n * 16) = pk;
        }
    }
}

// ---------------------------------------------------------------------------
// CSR gather: one 16-lane group per node (16 nodes / 256-thr block).
// ---------------------------------------------------------------------------
template <bool RELU>
__global__ void gather16(const uint4* __restrict__ hs4, const float* __restrict__ dinv,
                         const int* __restrict__ row_ptr, const int* __restrict__ edge_src,
                         const float* __restrict__ bias, uint4* __restrict__ out4, int n) {
    int node = blockIdx.x * 16 + (threadIdx.x >> 4);
    if (node >= n) return;
    int cl = threadIdx.x & 15;
    int beg = row_ptr[node], end = row_ptr[node + 1];
    f32x2 a[4] = {(f32x2){0.f,0.f}, (f32x2){0.f,0.f}, (f32x2){0.f,0.f}, (f32x2){0.f,0.f}};
    f32x2 b[4] = {(f32x2){0.f,0.f}, (f32x2){0.f,0.f}, (f32x2){0.f,0.f}, (f32x2){0.f,0.f}};
    acc8v(a, hs4[(size_t)node * 16 + cl]);   // self-loop
    int e = beg;
    for (; e + 4 <= end; e += 4) {
        uint4 v0 = hs4[(size_t)edge_src[e] * 16 + cl];
        uint4 v1 = hs4[(size_t)edge_src[e + 1] * 16 + cl];
        uint4 v2 = hs4[(size_t)edge_src[e + 2] * 16 + cl];
        uint4 v3 = hs4[(size_t)edge_src[e + 3] * 16 + cl];
        acc8v(a, v0);
        acc8v(b, v1);
        acc8v(a, v2);
        acc8v(b, v3);
    }
    if (e + 2 <= end) {
        uint4 v0 = hs4[(size_t)edge_src[e] * 16 + cl];
        uint4 v1 = hs4[(size_t)edge_src[e + 1] * 16 + cl];
        acc8v(a, v0);
        acc8v(b, v1);
        e += 2;
    }
    if (e < end) acc8v(a, hs4[(size_t)edge_src[e] * 16 + cl]);
#pragma unroll
    for (int i = 0; i < 4; i++) a[i] += b[i];
    float dv = dinv[node];
    float4 b0 = *reinterpret_cast<const float4*>(bias + cl * 8);
    float4 b1 = *reinterpret_cast<const float4*>(bias + cl * 8 + 4);
    float r0 = fmaf(a[0].x, dv, b0.x), r1 = fmaf(a[0].y, dv, b0.y);
    float r2 = fmaf(a[1].x, dv, b0.z), r3 = fmaf(a[1].y, dv, b0.w);
    float r4 = fmaf(a[2].x, dv, b1.x), r5 = fmaf(a[2].y, dv, b1.y);
    float r6 = fmaf(a[3].x, dv, b1.z), r7 = fmaf(a[3].y, dv, b1.w);
    if (RELU) {
        r0 = fmaxf(r0, 0.f); r1 = fmaxf(r1, 0.f); r2 = fmaxf(r2, 0.f); r3 = fmaxf(r3, 0.f);
        r4 = fmaxf(r4, 0.f); r5 = fmaxf(r5, 0.f); r6 = fmaxf(r6, 0.f); r7 = fmaxf(r7, 0.f);
    }
    uint4 o;
    o.x = pack2(r0, r1); o.y = pack2(r2, r3);
    o.z = pack2(r4, r5); o.w = pack2(r6, r7);
    out4[(size_t)node * 16 + cl] = o;
}

// final: t rows = [tm(64) | ts(64)] bf16 -> zm, zs fp32
__global__ void gather_dual(const uint4* __restrict__ hs4, const float* __restrict__ dinv,
                            const int* __restrict__ row_ptr, const int* __restrict__ edge_src,
                            const float* __restrict__ bm, const float* __restrict__ bs,
                            float* __restrict__ zm, float* __restrict__ zs, int n) {
    int node = blockIdx.x * 16 + (threadIdx.x >> 4);
    if (node >= n) return;
    int cl = threadIdx.x & 15;
    int beg = row_ptr[node], end = row_ptr[node + 1];
    f32x2 a[4] = {(f32x2){0.f,0.f}, (f32x2){0.f,0.f}, (f32x2){0.f,0.f}, (f32x2){0.f,0.f}};
    f32x2 b[4] = {(f32x2){0.f,0.f}, (f32x2){0.f,0.f}, (f32x2){0.f,0.f}, (f32x2){0.f,0.f}};
    acc8v(a, hs4[(size_t)node * 16 + cl]);
    int e = beg;
    for (; e + 4 <= end; e += 4) {
        uint4 v0 = hs4[(size_t)edge_src[e] * 16 + cl];
        uint4 v1 = hs4[(size_t)edge_src[e + 1] * 16 + cl];
        uint4 v2 = hs4[(size_t)edge_src[e + 2] * 16 + cl];
        uint4 v3 = hs4[(size_t)edge_src[e + 3] * 16 + cl];
        acc8v(a, v0);
        acc8v(b, v1);
        acc8v(a, v2);
        acc8v(b, v3);
    }
    if (e + 2 <= end) {
        uint4 v0 = hs4[(size_t)edge_src[e] * 16 + cl];
        uint4 v1 = hs4[(size_t)edge_src[e + 1] * 16 + cl];
        acc8v(a, v0);
        acc8v(b, v1);
        e += 2;
    }
    if (e < end) acc8v(a, hs4[(size_t)edge_src[e] * 16 + cl]);
#pragma unroll
    for (int i = 0; i < 4; i++) a[i] += b[i];
    float dv = dinv[node];
    const float* bp = (cl < 8) ? (bm + cl * 8) : (bs + (cl - 8) * 8);
    float* zp = (cl < 8) ? (zm + (size_t)node * 64 + cl * 8)
                         : (zs + (size_t)node * 64 + (cl - 8) * 8);
    float4 b0 = *reinterpret_cast<const float4*>(bp);
    float4 b1 = *reinterpret_cast<const float4*>(bp + 4);
    float4 o0 = make_float4(fmaf(a[0].x, dv, b0.x), fmaf(a[0].y, dv, b0.y),
                            fmaf(a[1].x, dv, b0.z), fmaf(a[1].y, dv, b0.w));
    float4 o1 = make_float4(fmaf(a[2].x, dv, b1.x), fmaf(a[2].y, dv, b1.y),
                            fmaf(a[3].x, dv, b1.z), fmaf(a[3].y, dv, b1.w));
    *reinterpret_cast<float4*>(zp) = o0;
    *reinterpret_cast<float4*>(zp + 4) = o1;
}

// ---------------------------------------------------------------------------

extern "C" void kernel_launch(void* const* d_in, const int* in_sizes, int n_in,
                              void* d_out, int out_size, void* d_ws, size_t ws_size,
                              hipStream_t stream) {
    const float* x     = (const float*)d_in[0];
    const float* noise = (const float*)d_in[1];
    const int*   ei    = (const int*)d_in[2];
    const float* gamma = (const float*)d_in[3];
    const float* beta  = (const float*)d_in[4];
    const float* W1    = (const float*)d_in[5];
    const float* b1    = (const float*)d_in[6];
    const float* W2    = (const float*)d_in[7];
    const float* b2    = (const float*)d_in[8];
    const float* Wm    = (const float*)d_in[9];
    const float* bm    = (const float*)d_in[10];
    const float* Ws    = (const float*)d_in[11];
    const float* bs    = (const float*)d_in[12];

    const int N  = in_sizes[0] / 128;
    const int E  = in_sizes[2] / 2;
    const int NPAD = (N + 127) & ~127;
    const int nb = (N + SCAN_ELEMS - 1) / SCAN_ELEMS;
    const int EB = (E + 255) / 256;
    const int CB = (N * 32 + 255) / 256;

    auto align256 = [](size_t b) { return (b + 255) & ~(size_t)255; };
    char* p = (char*)d_ws;
    int* cnt      = (int*)p;  p += align256((size_t)N * 4);
    int* row_ptr  = (int*)p;  p += align256((size_t)(N + 1) * 4);
    int* edge_src = (int*)p;  p += align256((size_t)E * 4);
    int* slot     = (int*)p;  p += align256((size_t)E * 4);
    int* bsums    = (int*)p;  p += align256((size_t)nb * 4);
    float* dinv   = (float*)p; p += align256((size_t)NPAD * 4);
    float* stats  = (float*)p; p += align256(512 * 4);
    float* cv1    = (float*)p; p += align256(128 * 4);
    float* cv2    = (float*)p; p += align256(128 * 4);
    float* cvc    = (float*)p; p += align256(128 * 4);
    float* bnpart = (float*)p; p += align256((size_t)256 * BN_G * 4);
    unsigned short* Wp1 = (unsigned short*)p; p += align256(128 * 128 * 2);
    unsigned short* Wp2 = (unsigned short*)p; p += align256(128 * 384 * 2);
    unsigned short* Wpc = (unsigned short*)p; p += align256(128 * 256 * 2);
    unsigned short* x16 = (unsigned short*)p; p += align256((size_t)NPAD * 128 * 2);
    unsigned short* n16 = (unsigned short*)p; p += align256((size_t)NPAD * 128 * 2);
    unsigned short* h16 = (unsigned short*)p; p += align256((size_t)NPAD * 128 * 2);

    float* scale = stats + 256;
    float* shift = stats + 384;

    float* dout = (float*)d_out;                       // N*128 fp32
    unsigned short* hs12 = (unsigned short*)d_out;     // conv1/2 hs scratch
    unsigned short* hs3  = n16;                        // noise dead after conv2
    float* zm = dout;                                  // [N*64]
    float* zs = dout + (size_t)N * 64;                 // [N*64]

    const int gblocks = NPAD / 64;
    const int nblocks16 = (N + 15) / 16;

    // --- fused setup DAG ---
    hipMemsetAsync(cnt, 0, (size_t)N * 4, stream);
    fused1<<<BN_G + EB, 256, 0, stream>>>((const float4*)x, bnpart, N,
                                          (ushort4*)x16, ei, cnt, slot, E);
    fused2<<<256 + nb, 256, 0, stream>>>((const float4*)bnpart, stats, cnt, row_ptr, bsums, N);
    fused3<<<1, 256, 0, stream>>>(bsums, nb, stats, gamma, beta, scale, shift, 1.0f / (float)N);
    fused4<<<(N + 255) / 256, 256, 0, stream>>>(row_ptr, bsums, cnt, dinv, N, E);
    fused5<<<EB + CB + 384 + 3, 256, 0, stream>>>(
        ei, row_ptr, slot, edge_src, E, EB,
        (const float4*)noise, (ushort4*)n16, N * 32, CB,
        scale, shift, W1, Wp1, W2, Wp2, Wm, Ws, Wpc, cv1, cv2, cvc);

    // conv1
    gemm_mfma<1><<<gblocks, 256, 0, stream>>>(x16, nullptr, nullptr, Wp1, dinv, cv1, hs12);
    gather16<true><<<nblocks16, 256, 0, stream>>>((const uint4*)hs12, dinv, row_ptr,
                                                  edge_src, b1, (uint4*)h16, N);
    // conv2
    gemm_mfma<3><<<gblocks, 256, 0, stream>>>(x16, n16, h16, Wp2, dinv, cv2, hs12);
    gather16<true><<<nblocks16, 256, 0, stream>>>((const uint4*)hs12, dinv, row_ptr,
                                                  edge_src, b2, (uint4*)h16, N);
    // mean/logstd fused
    gemm_mfma<2><<<gblocks, 256, 0, stream>>>(x16, h16, nullptr, Wpc, dinv, cvc, hs3);
    gather_dual<<<nblocks16, 256, 0, stream>>>((const uint4*)hs3, dinv, row_ptr,
                                               edge_src, bm, bs, zm, zs, N);
}